// Round 1
// baseline (240.896 us; speedup 1.0000x reference)
//
#include <hip/hip_runtime.h>

#define NEGF -3.402823466e38f

typedef __attribute__((ext_vector_type(8))) short bf16x8;
typedef __attribute__((ext_vector_type(4))) float f32x4;
typedef __attribute__((ext_vector_type(4))) unsigned short u16x4;

__device__ __forceinline__ unsigned short f2bf(float f) {
  unsigned u = __builtin_bit_cast(unsigned, f);
  u += 0x7fffu + ((u >> 16) & 1u);
  return (unsigned short)(u >> 16);
}

// ws layout in ushort units
#define OFF_QH  0u
#define OFF_KH  2097152u
#define OFF_W   4194304u      // 4 x 65536 (Wq,Wk,Wv,Wo)
#define OFF_QP  4456448u      // [B,H,S,D] bf16, pre-scaled by 1/8
#define OFF_KP  6553600u      // [B,H,S,D] bf16
#define OFF_VT  8650752u      // [B,H,D,S] bf16 (V transposed)
#define OFF_ATT 10747904u     // [B,S,256] bf16

// ---------------- f32 -> bf16 conversion of inputs ----------------
__global__ __launch_bounds__(256) void k_convert(
    const float* __restrict__ qh, const float* __restrict__ kh,
    const float* __restrict__ w0, const float* __restrict__ w1,
    const float* __restrict__ w2, const float* __restrict__ w3,
    unsigned short* __restrict__ dst) {
  int v = blockIdx.x * 256 + threadIdx.x;   // vector-of-4 index
  const float* src;
  if (v < 524288)       src = qh + (size_t)v * 4;
  else if (v < 1048576) src = kh + ((size_t)v - 524288) * 4;
  else {
    int t = v - 1048576;                    // 0 .. 65535
    int which = t >> 14;
    const float* w = (which == 0) ? w0 : (which == 1) ? w1 : (which == 2) ? w2 : w3;
    src = w + (size_t)(t & 16383) * 4;
  }
  f32x4 x = *(const f32x4*)src;
  u16x4 o;
  o[0] = f2bf(x[0]); o[1] = f2bf(x[1]); o[2] = f2bf(x[2]); o[3] = f2bf(x[3]);
  *(u16x4*)(dst + (size_t)v * 4) = o;
}

// ---------------- QKV projections ----------------
// y = x @ W^T ; x:(8192,256) bf16, W:(256,256) bf16 row-major (i.e. B^T layout)
__global__ __launch_bounds__(256) void k_proj(unsigned short* __restrict__ ws) {
  int bid = blockIdx.x;
  int mat = bid / 512;            // 0=Q 1=K 2=V
  int rem = bid - mat * 512;
  int mt = rem >> 2, nt = rem & 3;
  int tid = threadIdx.x, w = tid >> 6, lane = tid & 63;
  int l15 = lane & 15, l4 = lane >> 4;

  const unsigned short* X = ws + (mat == 0 ? OFF_QH : OFF_KH);
  const unsigned short* W = ws + OFF_W + (size_t)mat * 65536;

  int i0 = mt * 64 + w * 16;
  int arow = i0 + l15;
  int koff = l4 * 8;

  f32x4 acc[4] = {};
  for (int ks = 0; ks < 8; ++ks) {
    bf16x8 a = *(const bf16x8*)(X + (size_t)arow * 256 + ks * 32 + koff);
#pragma unroll
    for (int ct = 0; ct < 4; ++ct) {
      bf16x8 bb = *(const bf16x8*)(W + (size_t)(nt * 64 + ct * 16 + l15) * 256 + ks * 32 + koff);
      acc[ct] = __builtin_amdgcn_mfma_f32_16x16x32_bf16(a, bb, acc[ct], 0, 0, 0);
    }
  }

  unsigned short* Qp = ws + OFF_QP;
  unsigned short* Kp = ws + OFF_KP;
  unsigned short* Vt = ws + OFF_VT;
  int rbase = i0 + l4 * 4;
#pragma unroll
  for (int ct = 0; ct < 4; ++ct) {
#pragma unroll
    for (int r = 0; r < 4; ++r) {
      int row = rbase + r;
      int b = row >> 11, s = row & 2047;
      int d = ct * 16 + l15;
      float v = acc[ct][r];
      if (mat == 0)      Qp[((size_t)(b * 4 + nt) * 2048 + s) * 64 + d] = f2bf(v * 0.125f);
      else if (mat == 1) Kp[((size_t)(b * 4 + nt) * 2048 + s) * 64 + d] = f2bf(v);
      else               Vt[((size_t)(b * 4 + nt) * 64 + d) * 2048 + s] = f2bf(v);
    }
  }
}

// ---------------- fused masked flash attention ----------------
__global__ __launch_bounds__(256) void k_attn(unsigned short* __restrict__ ws,
    const float* __restrict__ amask, const int* __restrict__ alignm) {
  __shared__ __align__(16) unsigned short plds[4][1024];  // per-wave 16x64 bf16, XOR-swizzled

  int bh = blockIdx.x >> 5, qt = blockIdx.x & 31;
  int b = bh >> 2, h = bh & 3;
  int tid = threadIdx.x, w = tid >> 6, lane = tid & 63;
  int l15 = lane & 15, l4 = lane >> 4;
  int q0 = qt * 64 + w * 16;        // this wave's 16 q rows

  const unsigned short* Qp = ws + OFF_QP;
  const unsigned short* Kp = ws + OFF_KP;
  const unsigned short* Vt = ws + OFF_VT;
  const float* am = amask + (size_t)b * 2048 * 2048;
  const int* al = alignm + (size_t)b * 2048 * 2048;

  bf16x8 qf0 = *(const bf16x8*)(Qp + ((size_t)bh * 2048 + q0 + l15) * 64 + l4 * 8);
  bf16x8 qf1 = *(const bf16x8*)(Qp + ((size_t)bh * 2048 + q0 + l15) * 64 + 32 + l4 * 8);

  f32x4 o[4] = {};
  float mrun[4] = {-__builtin_inff(), -__builtin_inff(), -__builtin_inff(), -__builtin_inff()};
  float lrun[4] = {0.f, 0.f, 0.f, 0.f};

  for (int kk = 0; kk < 2048; kk += 64) {
    // ---- scores: S = (Q/8) @ K^T  (16 x 64 per wave) ----
    f32x4 sfr[4];
#pragma unroll
    for (int kt = 0; kt < 4; ++kt) {
      const unsigned short* kp = Kp + ((size_t)bh * 2048 + kk + kt * 16 + l15) * 64 + l4 * 8;
      bf16x8 k0 = *(const bf16x8*)kp;
      bf16x8 k1 = *(const bf16x8*)(kp + 32);
      f32x4 acc = {};
      acc = __builtin_amdgcn_mfma_f32_16x16x32_bf16(qf0, k0, acc, 0, 0, 0);
      acc = __builtin_amdgcn_mfma_f32_16x16x32_bf16(qf1, k1, acc, 0, 0, 0);
      sfr[kt] = acc;
    }
    // ---- masks ----
#pragma unroll
    for (int kt = 0; kt < 4; ++kt) {
      int kcol = kk + kt * 16 + l15;
#pragma unroll
      for (int r = 0; r < 4; ++r) {
        int qrow = q0 + l4 * 4 + r;
        float sc = sfr[kt][r] + am[(size_t)qrow * 2048 + kcol];
        sc = fmaxf(sc, NEGF);
        if (al[(size_t)kcol * 2048 + qrow] == 0) sc = NEGF;
        sfr[kt][r] = sc;
      }
    }
    // ---- online softmax ----
    float mnew[4], sfac[4];
#pragma unroll
    for (int r = 0; r < 4; ++r) {
      float rm = fmaxf(fmaxf(sfr[0][r], sfr[1][r]), fmaxf(sfr[2][r], sfr[3][r]));
      rm = fmaxf(rm, __shfl_xor(rm, 1));
      rm = fmaxf(rm, __shfl_xor(rm, 2));
      rm = fmaxf(rm, __shfl_xor(rm, 4));
      rm = fmaxf(rm, __shfl_xor(rm, 8));
      mnew[r] = fmaxf(mrun[r], rm);
      sfac[r] = __expf(mrun[r] - mnew[r]);
      mrun[r] = mnew[r];
    }
#pragma unroll
    for (int kt = 0; kt < 4; ++kt)
#pragma unroll
      for (int r = 0; r < 4; ++r)
        sfr[kt][r] = __expf(sfr[kt][r] - mnew[r]);
#pragma unroll
    for (int r = 0; r < 4; ++r) {
      float rs = sfr[0][r] + sfr[1][r] + sfr[2][r] + sfr[3][r];
      rs += __shfl_xor(rs, 1);
      rs += __shfl_xor(rs, 2);
      rs += __shfl_xor(rs, 4);
      rs += __shfl_xor(rs, 8);
      lrun[r] = lrun[r] * sfac[r] + rs;
      o[0][r] *= sfac[r]; o[1][r] *= sfac[r]; o[2][r] *= sfac[r]; o[3][r] *= sfac[r];
    }
    // ---- P (C-layout) -> LDS (XOR-swizzled) -> A-layout fragments ----
#pragma unroll
    for (int kt = 0; kt < 4; ++kt)
#pragma unroll
      for (int r = 0; r < 4; ++r) {
        int prow = l4 * 4 + r;
        int pcol = kt * 16 + l15;
        plds[w][prow * 64 + (((pcol >> 3) ^ (prow & 7)) << 3) + (pcol & 7)] = f2bf(sfr[kt][r]);
      }
    // ---- PV: O += P @ V ----
#pragma unroll
    for (int ks = 0; ks < 2; ++ks) {
      int chnk = ks * 4 + l4;
      bf16x8 pa = *(const bf16x8*)&plds[w][l15 * 64 + ((chnk ^ (l15 & 7)) << 3)];
#pragma unroll
      for (int dt = 0; dt < 4; ++dt) {
        const unsigned short* vp = Vt + ((size_t)bh * 64 + dt * 16 + l15) * 2048 + kk + ks * 32 + l4 * 8;
        bf16x8 vf = *(const bf16x8*)vp;
        o[dt] = __builtin_amdgcn_mfma_f32_16x16x32_bf16(pa, vf, o[dt], 0, 0, 0);
      }
    }
  }

  unsigned short* attnb = ws + OFF_ATT;
#pragma unroll
  for (int r = 0; r < 4; ++r) {
    float inv = 1.0f / lrun[r];
    int qrow = q0 + l4 * 4 + r;
#pragma unroll
    for (int dt = 0; dt < 4; ++dt)
      attnb[(size_t)(b * 2048 + qrow) * 256 + h * 64 + dt * 16 + l15] = f2bf(o[dt][r] * inv);
  }
}

// ---------------- output projection ----------------
__global__ __launch_bounds__(256) void k_oproj(const unsigned short* __restrict__ ws,
                                               float* __restrict__ out) {
  int bid = blockIdx.x;
  int mt = bid >> 2, nt = bid & 3;
  int tid = threadIdx.x, w = tid >> 6, lane = tid & 63;
  int l15 = lane & 15, l4 = lane >> 4;

  const unsigned short* A = ws + OFF_ATT;
  const unsigned short* W = ws + OFF_W + 3u * 65536u;   // Wo
  int i0 = mt * 64 + w * 16;

  f32x4 acc[4] = {};
  for (int ks = 0; ks < 8; ++ks) {
    bf16x8 a = *(const bf16x8*)(A + (size_t)(i0 + l15) * 256 + ks * 32 + l4 * 8);
#pragma unroll
    for (int ct = 0; ct < 4; ++ct) {
      bf16x8 bb = *(const bf16x8*)(W + (size_t)(nt * 64 + ct * 16 + l15) * 256 + ks * 32 + l4 * 8);
      acc[ct] = __builtin_amdgcn_mfma_f32_16x16x32_bf16(a, bb, acc[ct], 0, 0, 0);
    }
  }
#pragma unroll
  for (int ct = 0; ct < 4; ++ct)
#pragma unroll
    for (int r = 0; r < 4; ++r)
      out[(size_t)(i0 + l4 * 4 + r) * 256 + nt * 64 + ct * 16 + l15] = acc[ct][r];
}

extern "C" void kernel_launch(void* const* d_in, const int* in_sizes, int n_in,
                              void* d_out, int out_size, void* d_ws, size_t ws_size,
                              hipStream_t stream) {
  const float* qh = (const float*)d_in[0];
  const float* kh = (const float*)d_in[1];
  const float* amask = (const float*)d_in[2];
  const int* alignm = (const int*)d_in[3];
  const float* Wq = (const float*)d_in[4];
  const float* Wk = (const float*)d_in[5];
  const float* Wv = (const float*)d_in[6];
  const float* Wo = (const float*)d_in[7];
  float* out = (float*)d_out;
  unsigned short* ws = (unsigned short*)d_ws;

  k_convert<<<4352, 256, 0, stream>>>(qh, kh, Wq, Wk, Wv, Wo, ws);
  k_proj<<<1536, 256, 0, stream>>>(ws);
  k_attn<<<512, 256, 0, stream>>>(ws, amask, alignm);
  k_oproj<<<512, 256, 0, stream>>>(ws, out);
}

// Round 3
// 203.387 us; speedup vs baseline: 1.1844x; 1.1844x over previous
//
#include <hip/hip_runtime.h>

#define NEGF -3.402823466e38f
#define MASKED_F -3.38953139e38f   // bf16 0xFF7F, most-negative finite bf16

typedef __attribute__((ext_vector_type(8))) short bf16x8;
typedef __attribute__((ext_vector_type(4))) float f32x4;
typedef __attribute__((ext_vector_type(4))) unsigned short u16x4;

__device__ __forceinline__ unsigned short f2bf(float f) {
  unsigned u = __builtin_bit_cast(unsigned, f);
  u += 0x7fffu + ((u >> 16) & 1u);
  return (unsigned short)(u >> 16);
}

// ws layout in ushort units
#define OFF_QH  0u
#define OFF_KH  2097152u
#define OFF_W   4194304u      // 4 x 65536 (Wq,Wk,Wv,Wo)
#define OFF_QP  4456448u      // [B,H,S,D] bf16, pre-scaled by 1/8
#define OFF_KP  6553600u      // [B,H,S,D] bf16
#define OFF_VT  8650752u      // [B,H,D,S] bf16 (V transposed)
#define OFF_ATT 10747904u     // [B,S,256] bf16
#define OFF_M   12845056u     // [B][128][32][64][16] bf16 fragment-ordered combined mask (32 MB)

// ---------------- f32 -> bf16 conversion of inputs ----------------
__global__ __launch_bounds__(256) void k_convert(
    const float* __restrict__ qh, const float* __restrict__ kh,
    const float* __restrict__ w0, const float* __restrict__ w1,
    const float* __restrict__ w2, const float* __restrict__ w3,
    unsigned short* __restrict__ dst) {
  int v = blockIdx.x * 256 + threadIdx.x;   // vector-of-4 index
  const float* src;
  if (v < 524288)       src = qh + (size_t)v * 4;
  else if (v < 1048576) src = kh + ((size_t)v - 524288) * 4;
  else {
    int t = v - 1048576;                    // 0 .. 65535
    int which = t >> 14;
    const float* w = (which == 0) ? w0 : (which == 1) ? w1 : (which == 2) ? w2 : w3;
    src = w + (size_t)(t & 16383) * 4;
  }
  f32x4 x = *(const f32x4*)src;
  u16x4 o;
  o[0] = f2bf(x[0]); o[1] = f2bf(x[1]); o[2] = f2bf(x[2]); o[3] = f2bf(x[3]);
  *(u16x4*)(dst + (size_t)v * 4) = o;
}

// ---------------- combined-mask prepass ----------------
// M[b][q16][k64][lane][j], j = kt*4 + r covers (qrow = 16*q16 + (lane>>4)*4 + r,
// kcol = 64*k64 + kt*16 + (lane&15)).  Value = align==0 ? MASKED_F : amask  (bf16).
__global__ __launch_bounds__(256) void k_maskprep(const float* __restrict__ am,
    const int* __restrict__ al, unsigned short* __restrict__ M) {
  __shared__ float L[64 * 65];
  int bid = blockIdx.x;
  int b = bid >> 10, q64 = (bid >> 5) & 31, k64 = bid & 31;
  int t = threadIdx.x, c = t & 63, rg = t >> 6;

  const float* amb = am + ((size_t)b * 2048 + q64 * 64) * 2048 + k64 * 64;
#pragma unroll
  for (int i = 0; i < 16; ++i) {
    int row = i * 4 + rg;
    L[row * 65 + c] = amb[(size_t)row * 2048 + c];
  }
  __syncthreads();
  const int* alb = al + ((size_t)b * 2048 + k64 * 64) * 2048 + q64 * 64;
#pragma unroll
  for (int i = 0; i < 16; ++i) {
    int kr = i * 4 + rg;
    if (alb[(size_t)kr * 2048 + c] == 0) L[c * 65 + kr] = MASKED_F;
  }
  __syncthreads();
  int w = t >> 6, lane = t & 63, l15 = lane & 15, l4 = lane >> 4;
  unsigned short* outp = M + ((((size_t)(b * 128 + q64 * 4 + w)) * 32 + k64) * 64 + lane) * 16;
#pragma unroll
  for (int kt = 0; kt < 4; ++kt) {
    u16x4 o;
#pragma unroll
    for (int r = 0; r < 4; ++r)
      o[r] = f2bf(L[(w * 16 + l4 * 4 + r) * 65 + kt * 16 + l15]);
    *(u16x4*)(outp + kt * 4) = o;
  }
}

// ---------------- QKV projections ----------------
// y = x @ W^T ; x:(8192,256) bf16, W:(256,256) bf16 row-major (i.e. B^T layout)
__global__ __launch_bounds__(256) void k_proj(unsigned short* __restrict__ ws) {
  int bid = blockIdx.x;
  int mat = bid / 512;            // 0=Q 1=K 2=V
  int rem = bid - mat * 512;
  int mt = rem >> 2, nt = rem & 3;
  int tid = threadIdx.x, w = tid >> 6, lane = tid & 63;
  int l15 = lane & 15, l4 = lane >> 4;

  const unsigned short* X = ws + (mat == 0 ? OFF_QH : OFF_KH);
  const unsigned short* W = ws + OFF_W + (size_t)mat * 65536;

  int i0 = mt * 64 + w * 16;
  int arow = i0 + l15;
  int koff = l4 * 8;

  f32x4 acc[4] = {};
  for (int ks = 0; ks < 8; ++ks) {
    bf16x8 a = *(const bf16x8*)(X + (size_t)arow * 256 + ks * 32 + koff);
#pragma unroll
    for (int ct = 0; ct < 4; ++ct) {
      bf16x8 bb = *(const bf16x8*)(W + (size_t)(nt * 64 + ct * 16 + l15) * 256 + ks * 32 + koff);
      acc[ct] = __builtin_amdgcn_mfma_f32_16x16x32_bf16(a, bb, acc[ct], 0, 0, 0);
    }
  }

  unsigned short* Qp = ws + OFF_QP;
  unsigned short* Kp = ws + OFF_KP;
  unsigned short* Vt = ws + OFF_VT;
  int rbase = i0 + l4 * 4;
#pragma unroll
  for (int ct = 0; ct < 4; ++ct) {
#pragma unroll
    for (int r = 0; r < 4; ++r) {
      int row = rbase + r;
      int b = row >> 11, s = row & 2047;
      int d = ct * 16 + l15;
      float v = acc[ct][r];
      if (mat == 0)      Qp[((size_t)(b * 4 + nt) * 2048 + s) * 64 + d] = f2bf(v * 0.125f);
      else if (mat == 1) Kp[((size_t)(b * 4 + nt) * 2048 + s) * 64 + d] = f2bf(v);
      else               Vt[((size_t)(b * 4 + nt) * 64 + d) * 2048 + s] = f2bf(v);
    }
  }
}

// ---------------- fused masked flash attention ----------------
__global__ __launch_bounds__(256) void k_attn(unsigned short* __restrict__ ws) {
  __shared__ __align__(16) unsigned short plds[4][1024];  // per-wave 16x64 bf16, XOR-swizzled

  int bh = blockIdx.x >> 5, qt = blockIdx.x & 31;
  int b = bh >> 2, h = bh & 3;
  int tid = threadIdx.x, w = tid >> 6, lane = tid & 63;
  int l15 = lane & 15, l4 = lane >> 4;
  int q0 = qt * 64 + w * 16;        // this wave's 16 q rows

  const unsigned short* Qp = ws + OFF_QP;
  const unsigned short* Kp = ws + OFF_KP;
  const unsigned short* Vt = ws + OFF_VT;
  // fragment-ordered mask tile base for this wave's 16 q rows
  const unsigned short* Mw = ws + OFF_M +
      (((size_t)(b * 128 + qt * 4 + w)) * 32) * 1024 + (size_t)lane * 16;

  bf16x8 qf0 = *(const bf16x8*)(Qp + ((size_t)bh * 2048 + q0 + l15) * 64 + l4 * 8);
  bf16x8 qf1 = *(const bf16x8*)(Qp + ((size_t)bh * 2048 + q0 + l15) * 64 + 32 + l4 * 8);

  f32x4 o[4] = {};
  float mrun[4] = {-__builtin_inff(), -__builtin_inff(), -__builtin_inff(), -__builtin_inff()};
  float lrun[4] = {0.f, 0.f, 0.f, 0.f};

  for (int kk = 0; kk < 2048; kk += 64) {
    // ---- mask fragment loads (32 B / lane, contiguous; k-tile stride = 1024) ----
    const unsigned short* mp = Mw + ((size_t)(kk >> 6)) * 1024;
    bf16x8 m0 = *(const bf16x8*)mp;
    bf16x8 m1 = *(const bf16x8*)(mp + 8);
    // ---- scores: S = (Q/8) @ K^T  (16 x 64 per wave) ----
    f32x4 sfr[4];
#pragma unroll
    for (int kt = 0; kt < 4; ++kt) {
      const unsigned short* kp = Kp + ((size_t)bh * 2048 + kk + kt * 16 + l15) * 64 + l4 * 8;
      bf16x8 k0 = *(const bf16x8*)kp;
      bf16x8 k1 = *(const bf16x8*)(kp + 32);
      f32x4 acc = {};
      acc = __builtin_amdgcn_mfma_f32_16x16x32_bf16(qf0, k0, acc, 0, 0, 0);
      acc = __builtin_amdgcn_mfma_f32_16x16x32_bf16(qf1, k1, acc, 0, 0, 0);
      sfr[kt] = acc;
    }
    // ---- apply combined mask ----
#pragma unroll
    for (int kt = 0; kt < 4; ++kt) {
#pragma unroll
      for (int r = 0; r < 4; ++r) {
        int j = kt * 4 + r;
        unsigned short mu = (unsigned short)(j < 8 ? m0[j] : m1[j & 7]);
        float madd = __builtin_bit_cast(float, (unsigned)mu << 16);
        sfr[kt][r] = fmaxf(sfr[kt][r] + madd, NEGF);
      }
    }
    // ---- online softmax ----
    float mnew[4], sfac[4];
#pragma unroll
    for (int r = 0; r < 4; ++r) {
      float rm = fmaxf(fmaxf(sfr[0][r], sfr[1][r]), fmaxf(sfr[2][r], sfr[3][r]));
      rm = fmaxf(rm, __shfl_xor(rm, 1));
      rm = fmaxf(rm, __shfl_xor(rm, 2));
      rm = fmaxf(rm, __shfl_xor(rm, 4));
      rm = fmaxf(rm, __shfl_xor(rm, 8));
      mnew[r] = fmaxf(mrun[r], rm);
      sfac[r] = __expf(mrun[r] - mnew[r]);
      mrun[r] = mnew[r];
    }
#pragma unroll
    for (int kt = 0; kt < 4; ++kt)
#pragma unroll
      for (int r = 0; r < 4; ++r)
        sfr[kt][r] = __expf(sfr[kt][r] - mnew[r]);
#pragma unroll
    for (int r = 0; r < 4; ++r) {
      float rs = sfr[0][r] + sfr[1][r] + sfr[2][r] + sfr[3][r];
      rs += __shfl_xor(rs, 1);
      rs += __shfl_xor(rs, 2);
      rs += __shfl_xor(rs, 4);
      rs += __shfl_xor(rs, 8);
      lrun[r] = lrun[r] * sfac[r] + rs;
      o[0][r] *= sfac[r]; o[1][r] *= sfac[r]; o[2][r] *= sfac[r]; o[3][r] *= sfac[r];
    }
    // ---- P (C-layout) -> LDS (XOR-swizzled) -> A-layout fragments ----
#pragma unroll
    for (int kt = 0; kt < 4; ++kt)
#pragma unroll
      for (int r = 0; r < 4; ++r) {
        int prow = l4 * 4 + r;
        int pcol = kt * 16 + l15;
        plds[w][prow * 64 + (((pcol >> 3) ^ (prow & 7)) << 3) + (pcol & 7)] = f2bf(sfr[kt][r]);
      }
    // ---- PV: O += P @ V ----
#pragma unroll
    for (int ks = 0; ks < 2; ++ks) {
      int chnk = ks * 4 + l4;
      bf16x8 pa = *(const bf16x8*)&plds[w][l15 * 64 + ((chnk ^ (l15 & 7)) << 3)];
#pragma unroll
      for (int dt = 0; dt < 4; ++dt) {
        const unsigned short* vp = Vt + ((size_t)bh * 64 + dt * 16 + l15) * 2048 + kk + ks * 32 + l4 * 8;
        bf16x8 vf = *(const bf16x8*)vp;
        o[dt] = __builtin_amdgcn_mfma_f32_16x16x32_bf16(pa, vf, o[dt], 0, 0, 0);
      }
    }
  }

  unsigned short* attnb = ws + OFF_ATT;
#pragma unroll
  for (int r = 0; r < 4; ++r) {
    float inv = 1.0f / lrun[r];
    int qrow = q0 + l4 * 4 + r;
#pragma unroll
    for (int dt = 0; dt < 4; ++dt)
      attnb[(size_t)(b * 2048 + qrow) * 256 + h * 64 + dt * 16 + l15] = f2bf(o[dt][r] * inv);
  }
}

// ---------------- output projection ----------------
__global__ __launch_bounds__(256) void k_oproj(const unsigned short* __restrict__ ws,
                                               float* __restrict__ out) {
  int bid = blockIdx.x;
  int mt = bid >> 2, nt = bid & 3;
  int tid = threadIdx.x, w = tid >> 6, lane = tid & 63;
  int l15 = lane & 15, l4 = lane >> 4;

  const unsigned short* A = ws + OFF_ATT;
  const unsigned short* W = ws + OFF_W + 3u * 65536u;   // Wo
  int i0 = mt * 64 + w * 16;

  f32x4 acc[4] = {};
  for (int ks = 0; ks < 8; ++ks) {
    bf16x8 a = *(const bf16x8*)(A + (size_t)(i0 + l15) * 256 + ks * 32 + l4 * 8);
#pragma unroll
    for (int ct = 0; ct < 4; ++ct) {
      bf16x8 bb = *(const bf16x8*)(W + (size_t)(nt * 64 + ct * 16 + l15) * 256 + ks * 32 + l4 * 8);
      acc[ct] = __builtin_amdgcn_mfma_f32_16x16x32_bf16(a, bb, acc[ct], 0, 0, 0);
    }
  }
#pragma unroll
  for (int ct = 0; ct < 4; ++ct)
#pragma unroll
    for (int r = 0; r < 4; ++r)
      out[(size_t)(i0 + l4 * 4 + r) * 256 + nt * 64 + ct * 16 + l15] = acc[ct][r];
}

extern "C" void kernel_launch(void* const* d_in, const int* in_sizes, int n_in,
                              void* d_out, int out_size, void* d_ws, size_t ws_size,
                              hipStream_t stream) {
  const float* qh = (const float*)d_in[0];
  const float* kh = (const float*)d_in[1];
  const float* amask = (const float*)d_in[2];
  const int* alignm = (const int*)d_in[3];
  const float* Wq = (const float*)d_in[4];
  const float* Wk = (const float*)d_in[5];
  const float* Wv = (const float*)d_in[6];
  const float* Wo = (const float*)d_in[7];
  float* out = (float*)d_out;
  unsigned short* ws = (unsigned short*)d_ws;

  k_convert<<<4352, 256, 0, stream>>>(qh, kh, Wq, Wk, Wv, Wo, ws);
  k_maskprep<<<4096, 256, 0, stream>>>(amask, alignm, ws + OFF_M);
  k_proj<<<1536, 256, 0, stream>>>(ws);
  k_attn<<<512, 256, 0, stream>>>(ws);
  k_oproj<<<512, 256, 0, stream>>>(ws, out);
}